// Round 19
// baseline (1685.976 us; speedup 1.0000x reference)
//
#include <hip/hip_runtime.h>
#include <cstddef>
#include <cstdint>

#define B_ 512
#define T_ 2048
#define I_ 16
#define H_ 40

typedef __fp16 half_t;
typedef half_t h2 __attribute__((ext_vector_type(2)));
typedef float f4 __attribute__((ext_vector_type(4)));

// tanh(x) = 1 - 2/(exp(2x)+1); exp(2x) = exp2(x * 2*log2(e)).
__device__ __forceinline__ float fast_tanh(float x) {
  float e = __builtin_amdgcn_exp2f(x * 2.8853900817779268f);
  return 1.0f - 2.0f * __builtin_amdgcn_rcpf(e + 1.0f);
}

// f16 x f16 + f32 -> v_fma_mix_f32. Round-19 probe: ALL MACs are fmaf;
// ZERO volatile asm in the loop -> no async-register hazard possible.
__device__ __forceinline__ float fmx(half_t a, half_t b, float c) {
  return __builtin_fmaf((float)a, (float)b, c);
}
// f32 x f16 + f32 -> v_fma_mix_f32 (x consumed at full f32 precision).
__device__ __forceinline__ float fmxf(float a, half_t b, float c) {
  return __builtin_fmaf(a, (float)b, c);
}

#define PIN(v) asm volatile("" : "+v"(v))

// Pack one f32 weight row into resident half2 VGPRs (r4-proven with PIN).
#define LOADW(DST, SRC, STR, N2)                                    \
  _Pragma("unroll") for (int k = 0; k < (N2); ++k) {                \
    DST[k][0] = (half_t)SRC[jr * (STR) + 2 * k];                    \
    DST[k][1] = (half_t)SRC[jr * (STR) + 2 * k + 1];                \
    PIN(DST[k]);                                                    \
  }

// Register h broadcast via ds_bpermute (r15-proven):
// dpp XOR-1 -> cvt_pkrtz pair in even lane -> 20 uniform-addr bpermute.
#define BCAST(NH, PAIRS) do {                                       \
  int nb_ = __builtin_amdgcn_update_dpp(                            \
      0, __builtin_bit_cast(int, (NH)), 0xB1, 0xf, 0xf, false);     \
  h2 pk_ = __builtin_amdgcn_cvt_pkrtz((NH),                         \
      __builtin_bit_cast(float, nb_));                              \
  int pkb_ = __builtin_bit_cast(int, pk_);                          \
  _Pragma("unroll") for (int p = 0; p < H_ / 2; ++p)                \
    PAIRS[p] = __builtin_bit_cast(h2,                               \
        __builtin_amdgcn_ds_bpermute(8 * p, pkb_));                 \
} while (0)

// 40-wide h-dot as 40 v_fma_mix; accumulators rotate (same-acc uses 4
// instrs apart > 4-cyc FMA latency).
#define HDS(PAIRS, W, A0, A1, A2, A3)                               \
  _Pragma("unroll") for (int p = 0; p < 5; ++p) {                   \
    A0 = fmx(PAIRS[4 * p + 0][0], (W)[4 * p + 0][0], A0);           \
    A1 = fmx(PAIRS[4 * p + 1][0], (W)[4 * p + 1][0], A1);           \
    A2 = fmx(PAIRS[4 * p + 2][0], (W)[4 * p + 2][0], A2);           \
    A3 = fmx(PAIRS[4 * p + 3][0], (W)[4 * p + 3][0], A3);           \
    A0 = fmx(PAIRS[4 * p + 0][1], (W)[4 * p + 0][1], A0);           \
    A1 = fmx(PAIRS[4 * p + 1][1], (W)[4 * p + 1][1], A1);           \
    A2 = fmx(PAIRS[4 * p + 2][1], (W)[4 * p + 2][1], A2);           \
    A3 = fmx(PAIRS[4 * p + 3][1], (W)[4 * p + 3][1], A3);           \
  }

// 16-wide x dot off plain f32 registers (f32 x f16 fma_mix).
#define XDOT(R0, R1, R2, R3, A0, A1, A2, A3) do {                   \
  A0 = fmxf(R0[0], w0i[0][0], A0);                                  \
  A1 = fmxf(R0[1], w0i[0][1], A1);                                  \
  A2 = fmxf(R0[2], w0i[1][0], A2);                                  \
  A3 = fmxf(R0[3], w0i[1][1], A3);                                  \
  A0 = fmxf(R1[0], w0i[2][0], A0);                                  \
  A1 = fmxf(R1[1], w0i[2][1], A1);                                  \
  A2 = fmxf(R1[2], w0i[3][0], A2);                                  \
  A3 = fmxf(R1[3], w0i[3][1], A3);                                  \
  A0 = fmxf(R2[0], w0i[4][0], A0);                                  \
  A1 = fmxf(R2[1], w0i[4][1], A1);                                  \
  A2 = fmxf(R2[2], w0i[5][0], A2);                                  \
  A3 = fmxf(R2[3], w0i[5][1], A3);                                  \
  A0 = fmxf(R3[0], w0i[6][0], A0);                                  \
  A1 = fmxf(R3[1], w0i[6][1], A1);                                  \
  A2 = fmxf(R3[2], w0i[7][0], A2);                                  \
  A3 = fmxf(R3[3], w0i[7][1], A3);                                  \
} while (0)

// One RNN time step, zero LDS, zero inline-asm memory ops.
#define STEP(R0, R1, R2, R3) do {                                   \
  float a0 = bias0, a1 = 0.f, a2 = 0.f, a3 = 0.f;                   \
  XDOT(R0, R1, R2, R3, a0, a1, a2, a3);                             \
  HDS(hp0, w0h, a0, a1, a2, a3);  /* old h0 */                      \
  const float nh0 = fast_tanh((a0 + a1) + (a2 + a3));               \
  BCAST(nh0, hp0);                                                  \
  float b0 = bias1, b1 = 0.f, b2 = 0.f, b3 = 0.f;                   \
  HDS(hp0, w1i, b0, b1, b2, b3);  /* NEW h0 */                      \
  HDS(hp1, w1h, b0, b1, b2, b3);  /* old h1 */                      \
  const float nh1 = fast_tanh((b0 + b1) + (b2 + b3));               \
  BCAST(nh1, hp1);                                                  \
  float c0 = bias2, c1 = 0.f, c2 = 0.f, c3 = 0.f;                   \
  HDS(hp1, w2i, c0, c1, c2, c3);  /* NEW h1 */                      \
  HDS(hp2, w2h, c0, c1, c2, c3);  /* old h2 */                      \
  nh2v = fast_tanh((c0 + c1) + (c2 + c3));                          \
  BCAST(nh2v, hp2);                                                 \
} while (0)

// Plain C x load (r4-proven pattern): 4 float4 into named registers.
#define LOADX4(R0, R1, R2, R3, P) do {                              \
  const f4* q_ = (const f4*)(P);                                    \
  R0 = q_[0]; R1 = q_[1]; R2 = q_[2]; R3 = q_[3];                   \
} while (0)

__global__ __launch_bounds__(64)
__attribute__((amdgpu_waves_per_eu(1, 1)))  // full 512-reg budget
void rnn3_fused(const float* __restrict__ x,
                const float* __restrict__ wih0, const float* __restrict__ whh0,
                const float* __restrict__ bih0, const float* __restrict__ bhh0,
                const float* __restrict__ wih1, const float* __restrict__ whh1,
                const float* __restrict__ b_ih1, const float* __restrict__ bhh1,
                const float* __restrict__ wih2, const float* __restrict__ whh2,
                const float* __restrict__ bih2, const float* __restrict__ bhh2,
                const float* __restrict__ fcw, const float* __restrict__ fcb,
                float* __restrict__ out) {
  const int b = blockIdx.x;
  const int j = threadIdx.x;
  const int jr = (j < H_) ? j : (H_ - 1);

  // ---- weights packed fp16: 108 resident VGPRs ----
  h2 w0i[I_ / 2], w0h[H_ / 2], w1i[H_ / 2], w1h[H_ / 2], w2i[H_ / 2], w2h[H_ / 2];
  LOADW(w0i, wih0, I_, I_ / 2)
  LOADW(w0h, whh0, H_, H_ / 2)
  LOADW(w1i, wih1, H_, H_ / 2)
  LOADW(w1h, whh1, H_, H_ / 2)
  LOADW(w2i, wih2, H_, H_ / 2)
  LOADW(w2h, whh2, H_, H_ / 2)

  float bias0 = bih0[jr] + bhh0[jr];  PIN(bias0);
  float bias1 = b_ih1[jr] + bhh1[jr]; PIN(bias1);
  float bias2 = bih2[jr] + bhh2[jr];  PIN(bias2);

  // h state as 3x20 uniform VGPR fp16 pairs (h(0)=0)
  h2 hp0[H_ / 2], hp1[H_ / 2], hp2[H_ / 2];
#pragma unroll
  for (int p = 0; p < H_ / 2; ++p) {
    hp0[p] = h2{(half_t)0.f, (half_t)0.f};
    hp1[p] = h2{(half_t)0.f, (half_t)0.f};
    hp2[p] = h2{(half_t)0.f, (half_t)0.f};
  }

  const float* __restrict__ xb = x + (size_t)b * (T_ * I_);

  // Plain distance-2 prefetch, two f32 buffer sets (compiler-scheduled).
  f4 xA0, xA1, xA2, xA3, xB0, xB1, xB2, xB3;
  LOADX4(xA0, xA1, xA2, xA3, xb);        // t = 0
  LOADX4(xB0, xB1, xB2, xB3, xb + I_);   // t = 1

  float nh2v = 0.f;

  for (int t = 0; t < T_; t += 2) {
    STEP(xA0, xA1, xA2, xA3);
    { const int tf = (t + 2 < T_) ? t + 2 : T_ - 1;
      LOADX4(xA0, xA1, xA2, xA3, xb + (size_t)tf * I_); }
    STEP(xB0, xB1, xB2, xB3);
    { const int tf = (t + 3 < T_) ? t + 3 : T_ - 1;
      LOADX4(xB0, xB1, xB2, xB3, xb + (size_t)tf * I_); }
  }

  // ---- FC head: out[b] = sum_j fc_w[j]*h2[j] + fc_b ----
  const float fw = (j < H_) ? fcw[j] : 0.f;
  float v = nh2v * fw;
#pragma unroll
  for (int off = 32; off > 0; off >>= 1) v += __shfl_down(v, off);
  if (j == 0) out[b] = v + fcb[0];
}

extern "C" void kernel_launch(void* const* d_in, const int* in_sizes, int n_in,
                              void* d_out, int out_size, void* d_ws, size_t ws_size,
                              hipStream_t stream) {
  (void)in_sizes; (void)n_in; (void)d_ws; (void)ws_size; (void)out_size;
  const float* x    = (const float*)d_in[0];
  const float* wih0 = (const float*)d_in[1];
  const float* whh0 = (const float*)d_in[2];
  const float* bih0 = (const float*)d_in[3];
  const float* bhh0 = (const float*)d_in[4];
  const float* wih1 = (const float*)d_in[5];
  const float* whh1 = (const float*)d_in[6];
  const float* bih1 = (const float*)d_in[7];
  const float* bhh1 = (const float*)d_in[8];
  const float* wih2 = (const float*)d_in[9];
  const float* whh2 = (const float*)d_in[10];
  const float* bih2 = (const float*)d_in[11];
  const float* bhh2 = (const float*)d_in[12];
  const float* fcw  = (const float*)d_in[13];
  const float* fcb  = (const float*)d_in[14];
  float* out = (float*)d_out;

  hipLaunchKernelGGL(rnn3_fused, dim3(B_), dim3(64), 0, stream,
                     x, wih0, whh0, bih0, bhh0,
                     wih1, whh1, bih1, bhh1,
                     wih2, whh2, bih2, bhh2,
                     fcw, fcb, out);
}